// Round 4
// baseline (443.858 us; speedup 1.0000x reference)
//
#include <hip/hip_runtime.h>
#include <math.h>

#define NN 128
#define CC 256
#define HIDN 1024
#define EPSL 1e-6f

typedef short s16x8 __attribute__((ext_vector_type(8)));
typedef float f32x4 __attribute__((ext_vector_type(4)));

// ---- workspace layout ----
// bf16 units: wv blob [ct16][kt9][64][8]; wt blob [jt2][kt9][64][8]; sw2 blob [ct16][64][8];
// Wo bf16; fw1 bf16; fw2 bf16. f32: qt[1024][32], agg[1024][256], Wqt[256][32], qtc[32].
#define WVOFF    0
#define WTOFF    73728
#define SW2OFF   82944
#define WOB_OFF  91136
#define FW1B_OFF 156672
#define FW2B_OFF 418816
#define QT_BYTE_OFF   1361920
#define AGG_BYTE_OFF  1492992
#define WQT_BYTE_OFF  2541568
#define QTC_BYTE_OFF  2574336

__device__ __forceinline__ unsigned short f2b(float x) {
    unsigned u = __builtin_bit_cast(unsigned, x);
    u += 0x7fffu + ((u >> 16) & 1u);
    return (unsigned short)(u >> 16);
}
__device__ __forceinline__ float b2f(unsigned short s) {
    return __builtin_bit_cast(float, ((unsigned)s) << 16);
}
__device__ __forceinline__ float blo(unsigned u) { return b2f((unsigned short)u); }
__device__ __forceinline__ float bhi(unsigned u) { return b2f((unsigned short)(u >> 16)); }
__device__ __forceinline__ unsigned pack2(float a, float b) {
    return (unsigned)f2b(a) | ((unsigned)f2b(b) << 16);
}

__device__ __forceinline__ float block_sum_256(float v, float* red) {
    #pragma unroll
    for (int off = 32; off > 0; off >>= 1)
        v += __shfl_down(v, off, 64);
    const int wid = threadIdx.x >> 6;
    if ((threadIdx.x & 63) == 0) red[wid] = v;
    __syncthreads();
    float s = red[0] + red[1] + red[2] + red[3];
    __syncthreads();
    return s;
}

// ---------------- prep (merged): blobs + Wt + Wqt + qtc ----------------
__global__ __launch_bounds__(256)
void prep_all(const float* __restrict__ Wk, const float* __restrict__ Wv,
              const float* __restrict__ Wq,
              const float* __restrict__ pw2, const float* __restrict__ sw1,
              const float* __restrict__ sw2, const float* __restrict__ fw1,
              const float* __restrict__ fw2, const float* __restrict__ Wo,
              const float* __restrict__ pb2, const float* __restrict__ sb1,
              unsigned short* __restrict__ ws16,
              float* __restrict__ wqt, float* __restrict__ qtc)
{
    int e = blockIdx.x * 256 + threadIdx.x;   // 101632 total
    unsigned short v[8];
    if (e < 9216) {            // Wv blob (koct 36 x col 256)
        int koct = e >> 8, col = e & 255;
        #pragma unroll
        for (int j = 0; j < 8; ++j) {
            int k = koct * 8 + j;
            float val = (k < 256) ? Wv[k * 256 + col] : pw2[(k - 256) * 256 + col];
            v[j] = f2b(val);
        }
        int dest = WVOFF + (col >> 4) * 4608 + (koct >> 2) * 512
                 + (((((koct & 3) << 4) | (col & 15))) << 3);
        uint4 pk;
        pk.x = (unsigned)v[0] | ((unsigned)v[1] << 16);
        pk.y = (unsigned)v[2] | ((unsigned)v[3] << 16);
        pk.z = (unsigned)v[4] | ((unsigned)v[5] << 16);
        pk.w = (unsigned)v[6] | ((unsigned)v[7] << 16);
        *(uint4*)&ws16[dest] = pk;
    } else if (e < 10240) {    // sw2 blob
        int i = e - 9216;
        int koct = i & 3, col = i >> 2;
        #pragma unroll
        for (int j = 0; j < 8; ++j) v[j] = f2b(sw2[(koct * 8 + j) * 256 + col]);
        int dest = SW2OFF + (col >> 4) * 512 + ((((koct << 4) | (col & 15))) << 3);
        uint4 pk;
        pk.x = (unsigned)v[0] | ((unsigned)v[1] << 16);
        pk.y = (unsigned)v[2] | ((unsigned)v[3] << 16);
        pk.z = (unsigned)v[4] | ((unsigned)v[5] << 16);
        pk.w = (unsigned)v[6] | ((unsigned)v[7] << 16);
        *(uint4*)&ws16[dest] = pk;
    } else if (e < 83968) {    // linear bf16 copies
        const float* src; int base, i;
        if (e < 43008)      { src = fw1; base = FW1B_OFF; i = (e - 10240) * 8; }
        else if (e < 75776) { src = fw2; base = FW2B_OFF; i = (e - 43008) * 8; }
        else                { src = Wo;  base = WOB_OFF;  i = (e - 75776) * 8; }
        float4 a = *(const float4*)(src + i);
        float4 b = *(const float4*)(src + i + 4);
        uint4 pk;
        pk.x = pack2(a.x, a.y);
        pk.y = pack2(a.z, a.w);
        pk.z = pack2(b.x, b.y);
        pk.w = pack2(b.z, b.w);
        *(uint4*)&ws16[base + i] = pk;
    } else if (e < 93184) {    // Wt = (Wk | pw2) @ sw1
        int tid = e - 83968;
        int k = tid >> 5, j = tid & 31;
        const float* row = (k < 256) ? (Wk + (size_t)k * 256) : (pw2 + (size_t)(k - 256) * 256);
        float s = 0.0f;
        for (int c = 0; c < 256; ++c) s = fmaf(row[c], sw1[c * 32 + j], s);
        int dest = WTOFF + ((j >> 4) * 9 + (k >> 5)) * 512
                 + ((((((k >> 3) & 3) << 4) | (j & 15))) << 3) + (k & 7);
        ws16[dest] = f2b(s);
    } else if (e < 101376) {   // Wqt = Wq @ sw1 (fp32)
        int tid = e - 93184;
        int c = tid >> 5, j = tid & 31;
        const float* row = Wq + (size_t)c * 256;
        float s = 0.0f;
        for (int cp = 0; cp < 256; ++cp) s = fmaf(row[cp], sw1[cp * 32 + j], s);
        wqt[c * 32 + j] = s;
    } else {                   // qtc = pb2@sw1 + sb1
        int j = e - 101376;
        if (j < 32) {
            float s = sb1[j];
            for (int c = 0; c < 256; ++c) s = fmaf(pb2[c], sw1[c * 32 + j], s);
            qtc[j] = s;
        }
    }
}

// ---------------- qprep2: LN1 ; qt = qtc - xln@Wqt  (4 rows/block) ----------------
__global__ __launch_bounds__(256)
void qprep2(const float* __restrict__ qin,
            const float* __restrict__ ln1g, const float* __restrict__ ln1b,
            const float* __restrict__ wqt, const float* __restrict__ qtc,
            float* __restrict__ qt)
{
    __shared__ __align__(16) float xlnL[4][CC];
    const int t = threadIdx.x;
    const int lane = t & 63;
    const int r = t >> 6;
    const int b0 = blockIdx.x * 4;
    const size_t rowoff = (size_t)(b0 + r) * CC;

    float v0 = qin[rowoff + lane];
    float v1 = qin[rowoff + lane + 64];
    float v2 = qin[rowoff + lane + 128];
    float v3 = qin[rowoff + lane + 192];
    float s = v0 + v1 + v2 + v3;
    #pragma unroll
    for (int off = 32; off > 0; off >>= 1) s += __shfl_xor(s, off);
    float mean = s * (1.0f / CC);
    float d0 = v0 - mean, d1 = v1 - mean, d2 = v2 - mean, d3 = v3 - mean;
    float vs = d0 * d0 + d1 * d1 + d2 * d2 + d3 * d3;
    #pragma unroll
    for (int off = 32; off > 0; off >>= 1) vs += __shfl_xor(vs, off);
    float rstd = rsqrtf(vs * (1.0f / CC) + EPSL);
    xlnL[r][lane]       = d0 * rstd * ln1g[lane] + ln1b[lane];
    xlnL[r][lane + 64]  = d1 * rstd * ln1g[lane + 64] + ln1b[lane + 64];
    xlnL[r][lane + 128] = d2 * rstd * ln1g[lane + 128] + ln1b[lane + 128];
    xlnL[r][lane + 192] = d3 * rstd * ln1g[lane + 192] + ln1b[lane + 192];
    __syncthreads();

    if (t < 128) {
        int r2 = t >> 5, j = t & 31;
        float acc = qtc[j];
        for (int c = 0; c < 256; ++c) acc = fmaf(-xlnL[r2][c], wqt[c * 32 + j], acc);
        qt[(size_t)(b0 + r2) * 32 + j] = acc;
    }
}

// ---------------- attn: per (b,h), 256 threads / 4 waves ----------------
// Phase 0 (row-split): stage K bf16 into swizzled keyb; pos-MLP hidden -> aux; vis ballot.
// Phase 1 (row-split): H = relu((K|ph)@Wt + qterm) -> aux (swizzled).
// Phase 2 (ct-split, 4 ct/wave): single pass with per-lane ONLINE softmax.
//   Each lane tracks (m, ls, agg) over its 32 rows; quad-merge rescales by exp(m-mg).
__global__ __launch_bounds__(256, 2)
void cft_attn(const float* __restrict__ kin, const float* __restrict__ rel,
              const int* __restrict__ vis,
              const float* __restrict__ pw1, const float* __restrict__ pb1,
              const float* __restrict__ pb2, const float* __restrict__ sb2,
              const unsigned short* __restrict__ ws16,
              const float* __restrict__ qt,
              float* __restrict__ aggout)
{
    __shared__ __align__(16) unsigned char smem[81920];
    unsigned short* keyb = (unsigned short*)smem;            // [128][256] us, 16B-unit XOR swizzle (u ^= row&7)
    unsigned short* aux  = (unsigned short*)(smem + 65536);  // [128][64] us: H units 0-3, ph units 4-7, same swizzle

    const int bh = blockIdx.x;
    const int t = threadIdx.x;
    const int lane = t & 63;
    const int wvid = t >> 6;
    const int quad = lane >> 4;
    const int l16 = lane & 15;
    const int rb_w = wvid * 32;

    // ---- phase 0 ----
    const float4* kb4 = (const float4*)(kin + (size_t)bh * NN * CC);
    #pragma unroll
    for (int i = 0; i < 32; ++i) {
        int flat = i * 256 + t;
        int row = flat >> 6;
        int cu = flat & 63;                      // 8-byte unit within row
        float4 kv = kb4[flat];
        uint2 pk;
        pk.x = pack2(kv.x, kv.y);
        pk.y = pack2(kv.z, kv.w);
        int us = row * 256 + ((((cu >> 1) ^ (row & 7)) << 3) | ((cu & 1) << 2));
        *(uint2*)&keyb[us] = pk;
    }
    const unsigned long long vm0 = __ballot(vis[(size_t)bh * NN + lane] != 0);
    const unsigned long long vm1 = __ballot(vis[(size_t)bh * NN + 64 + lane] != 0);

    union { s16x8 v; unsigned short u[8]; } phf0, phf1;
    const int prow0 = rb_w + l16, prow1 = rb_w + 16 + l16;
    {
        float4 r40 = *(const float4*)(rel + ((size_t)bh * NN + prow0) * 4);
        float4 r41 = *(const float4*)(rel + ((size_t)bh * NN + prow1) * 4);
        #pragma unroll
        for (int j = 0; j < 8; ++j) {
            int col = quad * 8 + j;
            float w0 = pw1[col], w1 = pw1[32 + col], w2 = pw1[64 + col], w3 = pw1[96 + col];
            float b = pb1[col];
            float v0 = fmaf(r40.x, w0, fmaf(r40.y, w1, fmaf(r40.z, w2, fmaf(r40.w, w3, b))));
            float v1 = fmaf(r41.x, w0, fmaf(r41.y, w1, fmaf(r41.z, w2, fmaf(r41.w, w3, b))));
            phf0.u[j] = f2b(fmaxf(v0, 0.0f));
            phf1.u[j] = f2b(fmaxf(v1, 0.0f));
        }
        *(s16x8*)&aux[prow0 * 64 + (((4 + quad) ^ (prow0 & 7)) << 3)] = phf0.v;
        *(s16x8*)&aux[prow1 * 64 + (((4 + quad) ^ (prow1 & 7)) << 3)] = phf1.v;
    }
    const float qt0 = qt[(size_t)bh * 32 + l16];
    const float qt1 = qt[(size_t)bh * 32 + 16 + l16];
    __syncthreads();

    // ---- phase 1: H-GEMM (row-split) ----
    {
        const unsigned short* wst = ws16 + WTOFF;
        const int r0 = rb_w + l16;
        const int r1 = rb_w + 16 + l16;
        const int sw0 = r0 & 7;                  // == r1 & 7
        f32x4 hacc[2][2];
        #pragma unroll
        for (int mt = 0; mt < 2; ++mt)
            #pragma unroll
            for (int jt = 0; jt < 2; ++jt) hacc[mt][jt] = (f32x4){0.f, 0.f, 0.f, 0.f};
        #pragma unroll
        for (int kt = 0; kt < 8; ++kt) {
            s16x8 A0 = *(const s16x8*)&keyb[r0 * 256 + (((kt * 4 + quad) ^ sw0) << 3)];
            s16x8 A1 = *(const s16x8*)&keyb[r1 * 256 + (((kt * 4 + quad) ^ sw0) << 3)];
            #pragma unroll
            for (int jt = 0; jt < 2; ++jt) {
                s16x8 B = *(const s16x8*)(wst + (size_t)(jt * 9 + kt) * 512 + lane * 8);
                hacc[0][jt] = __builtin_amdgcn_mfma_f32_16x16x32_bf16(A0, B, hacc[0][jt], 0, 0, 0);
                hacc[1][jt] = __builtin_amdgcn_mfma_f32_16x16x32_bf16(A1, B, hacc[1][jt], 0, 0, 0);
            }
        }
        #pragma unroll
        for (int jt = 0; jt < 2; ++jt) {
            s16x8 B = *(const s16x8*)(wst + (size_t)(jt * 9 + 8) * 512 + lane * 8);
            hacc[0][jt] = __builtin_amdgcn_mfma_f32_16x16x32_bf16(phf0.v, B, hacc[0][jt], 0, 0, 0);
            hacc[1][jt] = __builtin_amdgcn_mfma_f32_16x16x32_bf16(phf1.v, B, hacc[1][jt], 0, 0, 0);
        }
        #pragma unroll
        for (int mt = 0; mt < 2; ++mt)
            #pragma unroll
            for (int jt = 0; jt < 2; ++jt) {
                float qv = jt ? qt1 : qt0;
                #pragma unroll
                for (int r = 0; r < 4; ++r) {
                    int n = rb_w + mt * 16 + quad * 4 + r;
                    int col = jt * 16 + l16;
                    aux[n * 64 + (((col >> 3) ^ (n & 7)) << 3) + (col & 7)] =
                        f2b(fmaxf(hacc[mt][jt][r] + qv, 0.0f));
                }
            }
    }
    __syncthreads();

    // ---- phase 2: ct-split, single pass, online softmax ----
    const unsigned short* wsv = ws16 + WVOFF;
    const unsigned short* ws2 = ws16 + SW2OFF;

    #pragma unroll 1
    for (int ck = 0; ck < 2; ++ck) {
        const int ct0 = wvid * 4 + ck * 2;
        s16x8 Bs0 = *(const s16x8*)(ws2 + ((size_t)ct0 * 64 + lane) * 8);
        s16x8 Bs1 = *(const s16x8*)(ws2 + ((size_t)(ct0 + 1) * 64 + lane) * 8);
        const float sb2c0 = sb2[ct0 * 16 + l16];
        const float sb2c1 = sb2[(ct0 + 1) * 16 + l16];
        const float pbv0 = pb2[ct0 * 16 + l16];
        const float pbv1 = pb2[(ct0 + 1) * 16 + l16];

        s16x8 Bv0[9], Bv1[9];
        #pragma unroll
        for (int kt = 0; kt < 9; ++kt) {
            Bv0[kt] = *(const s16x8*)(wsv + (size_t)(ct0 * 9 + kt) * 512 + lane * 8);
            Bv1[kt] = *(const s16x8*)(wsv + (size_t)((ct0 + 1) * 9 + kt) * 512 + lane * 8);
        }

        float ml0 = -3.0e38f, ml1 = -3.0e38f;
        float ls0 = 0.f, ls1 = 0.f, agg0 = 0.f, agg1 = 0.f;

        #pragma unroll
        for (int rb = 0; rb < 8; ++rb) {
            const int n0 = rb * 16 + l16;
            const int sw0 = n0 & 7;
            const unsigned short* arow = &keyb[n0 * 256];
            s16x8 H  = *(const s16x8*)&aux[n0 * 64 + ((quad ^ sw0) << 3)];
            s16x8 PH = *(const s16x8*)&aux[n0 * 64 + (((4 + quad) ^ sw0) << 3)];
            f32x4 a0 = (f32x4){0.f, 0.f, 0.f, 0.f};
            f32x4 a1 = (f32x4){0.f, 0.f, 0.f, 0.f};
            a0 = __builtin_amdgcn_mfma_f32_16x16x32_bf16(H, Bs0, a0, 0, 0, 0);
            a1 = __builtin_amdgcn_mfma_f32_16x16x32_bf16(H, Bs1, a1, 0, 0, 0);
            f32x4 v0a = (f32x4){0.f, 0.f, 0.f, 0.f};
            f32x4 v1a = (f32x4){0.f, 0.f, 0.f, 0.f};
            #pragma unroll
            for (int kt = 0; kt < 8; ++kt) {
                s16x8 A = *(const s16x8*)&arow[(((kt * 4 + quad) ^ sw0) << 3)];
                v0a = __builtin_amdgcn_mfma_f32_16x16x32_bf16(A, Bv0[kt], v0a, 0, 0, 0);
                v1a = __builtin_amdgcn_mfma_f32_16x16x32_bf16(A, Bv1[kt], v1a, 0, 0, 0);
            }
            v0a = __builtin_amdgcn_mfma_f32_16x16x32_bf16(PH, Bv0[8], v0a, 0, 0, 0);
            v1a = __builtin_amdgcn_mfma_f32_16x16x32_bf16(PH, Bv1[8], v1a, 0, 0, 0);

            const unsigned long long m = (rb < 4) ? vm0 : vm1;
            const int nb = (rb * 16) & 63;
            float sc0[4], sc1[4];
            #pragma unroll
            for (int r = 0; r < 4; ++r) {
                bool vv = (m >> (nb + quad * 4 + r)) & 1;
                sc0[r] = vv ? (a0[r] + sb2c0) : -1e9f;
                sc1[r] = vv ? (a1[r] + sb2c1) : -1e9f;
            }
            // online update ct0
            {
                float pm = fmaxf(fmaxf(sc0[0], sc0[1]), fmaxf(sc0[2], sc0[3]));
                float mn = fmaxf(ml0, pm);
                float scl = __expf(ml0 - mn);
                float e0 = __expf(sc0[0] - mn);
                float e1 = __expf(sc0[1] - mn);
                float e2 = __expf(sc0[2] - mn);
                float e3 = __expf(sc0[3] - mn);
                float sls = e0 + e1 + e2 + e3;
                float sag = fmaf(e0, v0a[0] + pbv0,
                            fmaf(e1, v0a[1] + pbv0,
                            fmaf(e2, v0a[2] + pbv0,
                                 e3 * (v0a[3] + pbv0))));
                ls0 = fmaf(ls0, scl, sls);
                agg0 = fmaf(agg0, scl, sag);
                ml0 = mn;
            }
            // online update ct1
            {
                float pm = fmaxf(fmaxf(sc1[0], sc1[1]), fmaxf(sc1[2], sc1[3]));
                float mn = fmaxf(ml1, pm);
                float scl = __expf(ml1 - mn);
                float e0 = __expf(sc1[0] - mn);
                float e1 = __expf(sc1[1] - mn);
                float e2 = __expf(sc1[2] - mn);
                float e3 = __expf(sc1[3] - mn);
                float sls = e0 + e1 + e2 + e3;
                float sag = fmaf(e0, v1a[0] + pbv1,
                            fmaf(e1, v1a[1] + pbv1,
                            fmaf(e2, v1a[2] + pbv1,
                                 e3 * (v1a[3] + pbv1))));
                ls1 = fmaf(ls1, scl, sls);
                agg1 = fmaf(agg1, scl, sag);
                ml1 = mn;
            }
        }

        // quad-merge: rescale by exp(m - mg), then sum
        float mg0 = fmaxf(ml0, __shfl_xor(ml0, 16));
        mg0 = fmaxf(mg0, __shfl_xor(mg0, 32));
        float f0 = __expf(ml0 - mg0);
        agg0 *= f0; ls0 *= f0;
        float mg1 = fmaxf(ml1, __shfl_xor(ml1, 16));
        mg1 = fmaxf(mg1, __shfl_xor(mg1, 32));
        float f1 = __expf(ml1 - mg1);
        agg1 *= f1; ls1 *= f1;

        agg0 += __shfl_xor(agg0, 16); agg0 += __shfl_xor(agg0, 32);
        ls0  += __shfl_xor(ls0, 16);  ls0  += __shfl_xor(ls0, 32);
        agg1 += __shfl_xor(agg1, 16); agg1 += __shfl_xor(agg1, 32);
        ls1  += __shfl_xor(ls1, 16);  ls1  += __shfl_xor(ls1, 32);
        if (lane < 16) {
            aggout[(size_t)bh * CC + ct0 * 16 + l16]       = agg0 / ls0;
            aggout[(size_t)bh * CC + (ct0 + 1) * 16 + l16] = agg1 / ls1;
        }
    }
}

// ---------------- ffo2: Wo + LN2 + FF, 2 rows/block, packed uint weight loads ----------------
__global__ __launch_bounds__(256, 4)
void cft_ffo2(const float* __restrict__ aggp, const float* __restrict__ qin,
              const float* __restrict__ bo,
              const float* __restrict__ ln2g, const float* __restrict__ ln2b,
              const unsigned short* __restrict__ ws16,
              const float* __restrict__ fb1, const float* __restrict__ fb2,
              float* __restrict__ out)
{
    __shared__ __align__(16) float aggL[2][CC];
    __shared__ __align__(16) float xlnL[2][CC];
    __shared__ __align__(16) float ffh[2][HIDN];
    __shared__ __align__(16) float part[2][2][CC];   // [half][row][c]
    __shared__ float red[4];
    const int t = threadIdx.x;
    const int b0 = blockIdx.x * 2;
    const unsigned short* wob  = ws16 + WOB_OFF;
    const unsigned short* fw1b = ws16 + FW1B_OFF;
    const unsigned short* fw2b = ws16 + FW2B_OFF;

    float xq[2];
    #pragma unroll
    for (int i = 0; i < 2; ++i) {
        aggL[i][t] = aggp[(size_t)(b0 + i) * CC + t];
        xq[i] = qin[(size_t)(b0 + i) * CC + t];
    }
    __syncthreads();

    // Wo matvec (c = t)
    float ao[2];
    { float b = bo[t]; ao[0] = b; ao[1] = b; }
    for (int k4 = 0; k4 < CC / 4; ++k4) {
        float4 a0 = *(const float4*)&aggL[0][k4 * 4];
        float4 a1 = *(const float4*)&aggL[1][k4 * 4];
        const unsigned short* w = wob + (size_t)(k4 * 4) * CC + t;
        float w0 = b2f(w[0]), w1 = b2f(w[CC]), w2 = b2f(w[2 * CC]), w3 = b2f(w[3 * CC]);
        ao[0] = fmaf(a0.x, w0, fmaf(a0.y, w1, fmaf(a0.z, w2, fmaf(a0.w, w3, ao[0]))));
        ao[1] = fmaf(a1.x, w0, fmaf(a1.y, w1, fmaf(a1.z, w2, fmaf(a1.w, w3, ao[1]))));
    }
    float xrs[2] = { ao[0] + xq[0], ao[1] + xq[1] };

    // LN2
    #pragma unroll
    for (int row = 0; row < 2; ++row) {
        float x = xrs[row];
        float mean = block_sum_256(x, red) * (1.0f / CC);
        float d = x - mean;
        float var = block_sum_256(d * d, red) * (1.0f / CC);
        xlnL[row][t] = d * rsqrtf(var + EPSL) * ln2g[t] + ln2b[t];
    }
    __syncthreads();

    // ff1: h = {2t, 2t+1, 2t+512, 2t+513}; packed uint loads (4B/lane)
    {
        const int h0 = 2 * t;
        float acc[2][4];
        acc[0][0] = acc[1][0] = fb1[h0];
        acc[0][1] = acc[1][1] = fb1[h0 + 1];
        acc[0][2] = acc[1][2] = fb1[h0 + 512];
        acc[0][3] = acc[1][3] = fb1[h0 + 513];
        for (int k4 = 0; k4 < CC / 4; ++k4) {
            float4 x0 = *(const float4*)&xlnL[0][k4 * 4];
            float4 x1 = *(const float4*)&xlnL[1][k4 * 4];
            float xa0[4] = {x0.x, x0.y, x0.z, x0.w};
            float xa1[4] = {x1.x, x1.y, x1.z, x1.w};
            #pragma unroll
            for (int kk = 0; kk < 4; ++kk) {
                const int k = k4 * 4 + kk;
                unsigned wA = *(const unsigned*)&fw1b[(size_t)k * HIDN + h0];
                unsigned wB = *(const unsigned*)&fw1b[(size_t)k * HIDN + h0 + 512];
                float wl = blo(wA), wh = bhi(wA), wl2 = blo(wB), wh2 = bhi(wB);
                acc[0][0] = fmaf(xa0[kk], wl, acc[0][0]);
                acc[0][1] = fmaf(xa0[kk], wh, acc[0][1]);
                acc[0][2] = fmaf(xa0[kk], wl2, acc[0][2]);
                acc[0][3] = fmaf(xa0[kk], wh2, acc[0][3]);
                acc[1][0] = fmaf(xa1[kk], wl, acc[1][0]);
                acc[1][1] = fmaf(xa1[kk], wh, acc[1][1]);
                acc[1][2] = fmaf(xa1[kk], wl2, acc[1][2]);
                acc[1][3] = fmaf(xa1[kk], wh2, acc[1][3]);
            }
        }
        #pragma unroll
        for (int row = 0; row < 2; ++row) {
            ffh[row][h0]       = fmaxf(acc[row][0], 0.0f);
            ffh[row][h0 + 1]   = fmaxf(acc[row][1], 0.0f);
            ffh[row][h0 + 512] = fmaxf(acc[row][2], 0.0f);
            ffh[row][h0 + 513] = fmaxf(acc[row][3], 0.0f);
        }
    }
    __syncthreads();

    // ff2: half the threads per h-half, c-pairs; packed uint loads
    {
        const int u = t & 127;
        const int half = t >> 7;
        const int c0 = 2 * u;
        const int hbase = half * 512;
        float oacc[2][2] = {{0.f, 0.f}, {0.f, 0.f}};   // [row][c-slot]
        for (int h4 = 0; h4 < 128; ++h4) {
            const int h = hbase + h4 * 4;
            #pragma unroll
            for (int hh = 0; hh < 4; ++hh) {
                unsigned w = *(const unsigned*)&fw2b[(size_t)(h + hh) * CC + c0];
                float w0 = blo(w), w1 = bhi(w);
                float hv0 = ffh[0][h + hh];
                float hv1 = ffh[1][h + hh];
                oacc[0][0] = fmaf(hv0, w0, oacc[0][0]);
                oacc[0][1] = fmaf(hv0, w1, oacc[0][1]);
                oacc[1][0] = fmaf(hv1, w0, oacc[1][0]);
                oacc[1][1] = fmaf(hv1, w1, oacc[1][1]);
            }
        }
        part[half][0][c0]     = oacc[0][0];
        part[half][0][c0 + 1] = oacc[0][1];
        part[half][1][c0]     = oacc[1][0];
        part[half][1][c0 + 1] = oacc[1][1];
    }
    __syncthreads();
    #pragma unroll
    for (int row = 0; row < 2; ++row)
        out[(size_t)(b0 + row) * CC + t] =
            xrs[row] + fb2[t] + part[0][row][t] + part[1][row][t];
}

extern "C" void kernel_launch(void* const* d_in, const int* in_sizes, int n_in,
                              void* d_out, int out_size, void* d_ws, size_t ws_size,
                              hipStream_t stream) {
    const float* qin  = (const float*)d_in[0];
    const float* kin  = (const float*)d_in[1];
    const float* rel  = (const float*)d_in[2];
    const int*   vis  = (const int*)  d_in[3];
    const float* ln1g = (const float*)d_in[4];
    const float* ln1b = (const float*)d_in[5];
    const float* ln2g = (const float*)d_in[6];
    const float* ln2b = (const float*)d_in[7];
    const float* Wq   = (const float*)d_in[8];
    const float* Wk   = (const float*)d_in[9];
    const float* Wv   = (const float*)d_in[10];
    const float* pw1  = (const float*)d_in[11];
    const float* pb1  = (const float*)d_in[12];
    const float* pw2  = (const float*)d_in[13];
    const float* pb2  = (const float*)d_in[14];
    const float* sw1  = (const float*)d_in[15];
    const float* sb1  = (const float*)d_in[16];
    const float* sw2  = (const float*)d_in[17];
    const float* sb2  = (const float*)d_in[18];
    const float* Wo   = (const float*)d_in[19];
    const float* bo   = (const float*)d_in[20];
    const float* fw1  = (const float*)d_in[21];
    const float* fb1  = (const float*)d_in[22];
    const float* fw2  = (const float*)d_in[23];
    const float* fb2  = (const float*)d_in[24];
    (void)in_sizes; (void)n_in; (void)out_size; (void)ws_size;

    unsigned short* ws16 = (unsigned short*)d_ws;
    float* qt   = (float*)((char*)d_ws + QT_BYTE_OFF);
    float* aggb = (float*)((char*)d_ws + AGG_BYTE_OFF);
    float* wqt  = (float*)((char*)d_ws + WQT_BYTE_OFF);
    float* qtc  = (float*)((char*)d_ws + QTC_BYTE_OFF);
    float* o = (float*)d_out;

    prep_all<<<dim3(397), dim3(256), 0, stream>>>(
        Wk, Wv, Wq, pw2, sw1, sw2, fw1, fw2, Wo, pb2, sb1, ws16, wqt, qtc);
    qprep2<<<dim3(256), dim3(256), 0, stream>>>(qin, ln1g, ln1b, wqt, qtc, qt);
    cft_attn<<<dim3(1024), dim3(256), 0, stream>>>(
        kin, rel, vis, pw1, pb1, pb2, sb2, ws16, qt, aggb);
    cft_ffo2<<<dim3(512), dim3(256), 0, stream>>>(
        aggb, qin, bo, ln2g, ln2b, ws16, fb1, fb2, o);
}

// Round 5
// 329.008 us; speedup vs baseline: 1.3491x; 1.3491x over previous
//
#include <hip/hip_runtime.h>
#include <math.h>

#define NN 128
#define CC 256
#define HIDN 1024
#define EPSL 1e-6f

typedef short s16x8 __attribute__((ext_vector_type(8)));
typedef float f32x4 __attribute__((ext_vector_type(4)));

// ---- workspace layout ----
// bf16 units: wv blob [ct16][kt9][64][8]; wt blob [jt2][kt9][64][8]; sw2 blob [ct16][64][8];
// Wo bf16; fw1 bf16; fw2 bf16. f32: qt[1024][32], agg[1024][256], Wqt[256][32], qtc[32].
#define WVOFF    0
#define WTOFF    73728
#define SW2OFF   82944
#define WOB_OFF  91136
#define FW1B_OFF 156672
#define FW2B_OFF 418816
#define QT_BYTE_OFF   1361920
#define AGG_BYTE_OFF  1492992
#define WQT_BYTE_OFF  2541568
#define QTC_BYTE_OFF  2574336

__device__ __forceinline__ unsigned short f2b(float x) {
    unsigned u = __builtin_bit_cast(unsigned, x);
    u += 0x7fffu + ((u >> 16) & 1u);
    return (unsigned short)(u >> 16);
}
__device__ __forceinline__ float b2f(unsigned short s) {
    return __builtin_bit_cast(float, ((unsigned)s) << 16);
}
__device__ __forceinline__ float blo(unsigned u) { return b2f((unsigned short)u); }
__device__ __forceinline__ float bhi(unsigned u) { return b2f((unsigned short)(u >> 16)); }
__device__ __forceinline__ unsigned pack2(float a, float b) {
    return (unsigned)f2b(a) | ((unsigned)f2b(b) << 16);
}

__device__ __forceinline__ float block_sum_256(float v, float* red) {
    #pragma unroll
    for (int off = 32; off > 0; off >>= 1)
        v += __shfl_down(v, off, 64);
    const int wid = threadIdx.x >> 6;
    if ((threadIdx.x & 63) == 0) red[wid] = v;
    __syncthreads();
    float s = red[0] + red[1] + red[2] + red[3];
    __syncthreads();
    return s;
}

// ---------------- prep (merged): blobs + Wt + Wqt + qtc ----------------
__global__ __launch_bounds__(256)
void prep_all(const float* __restrict__ Wk, const float* __restrict__ Wv,
              const float* __restrict__ Wq,
              const float* __restrict__ pw2, const float* __restrict__ sw1,
              const float* __restrict__ sw2, const float* __restrict__ fw1,
              const float* __restrict__ fw2, const float* __restrict__ Wo,
              const float* __restrict__ pb2, const float* __restrict__ sb1,
              unsigned short* __restrict__ ws16,
              float* __restrict__ wqt, float* __restrict__ qtc)
{
    int e = blockIdx.x * 256 + threadIdx.x;   // 101632 total
    unsigned short v[8];
    if (e < 9216) {            // Wv blob (koct 36 x col 256)
        int koct = e >> 8, col = e & 255;
        #pragma unroll
        for (int j = 0; j < 8; ++j) {
            int k = koct * 8 + j;
            float val = (k < 256) ? Wv[k * 256 + col] : pw2[(k - 256) * 256 + col];
            v[j] = f2b(val);
        }
        int dest = WVOFF + (col >> 4) * 4608 + (koct >> 2) * 512
                 + (((((koct & 3) << 4) | (col & 15))) << 3);
        uint4 pk;
        pk.x = (unsigned)v[0] | ((unsigned)v[1] << 16);
        pk.y = (unsigned)v[2] | ((unsigned)v[3] << 16);
        pk.z = (unsigned)v[4] | ((unsigned)v[5] << 16);
        pk.w = (unsigned)v[6] | ((unsigned)v[7] << 16);
        *(uint4*)&ws16[dest] = pk;
    } else if (e < 10240) {    // sw2 blob
        int i = e - 9216;
        int koct = i & 3, col = i >> 2;
        #pragma unroll
        for (int j = 0; j < 8; ++j) v[j] = f2b(sw2[(koct * 8 + j) * 256 + col]);
        int dest = SW2OFF + (col >> 4) * 512 + ((((koct << 4) | (col & 15))) << 3);
        uint4 pk;
        pk.x = (unsigned)v[0] | ((unsigned)v[1] << 16);
        pk.y = (unsigned)v[2] | ((unsigned)v[3] << 16);
        pk.z = (unsigned)v[4] | ((unsigned)v[5] << 16);
        pk.w = (unsigned)v[6] | ((unsigned)v[7] << 16);
        *(uint4*)&ws16[dest] = pk;
    } else if (e < 83968) {    // linear bf16 copies
        const float* src; int base, i;
        if (e < 43008)      { src = fw1; base = FW1B_OFF; i = (e - 10240) * 8; }
        else if (e < 75776) { src = fw2; base = FW2B_OFF; i = (e - 43008) * 8; }
        else                { src = Wo;  base = WOB_OFF;  i = (e - 75776) * 8; }
        float4 a = *(const float4*)(src + i);
        float4 b = *(const float4*)(src + i + 4);
        uint4 pk;
        pk.x = pack2(a.x, a.y);
        pk.y = pack2(a.z, a.w);
        pk.z = pack2(b.x, b.y);
        pk.w = pack2(b.z, b.w);
        *(uint4*)&ws16[base + i] = pk;
    } else if (e < 93184) {    // Wt = (Wk | pw2) @ sw1
        int tid = e - 83968;
        int k = tid >> 5, j = tid & 31;
        const float* row = (k < 256) ? (Wk + (size_t)k * 256) : (pw2 + (size_t)(k - 256) * 256);
        float s = 0.0f;
        for (int c = 0; c < 256; ++c) s = fmaf(row[c], sw1[c * 32 + j], s);
        int dest = WTOFF + ((j >> 4) * 9 + (k >> 5)) * 512
                 + ((((((k >> 3) & 3) << 4) | (j & 15))) << 3) + (k & 7);
        ws16[dest] = f2b(s);
    } else if (e < 101376) {   // Wqt = Wq @ sw1 (fp32)
        int tid = e - 93184;
        int c = tid >> 5, j = tid & 31;
        const float* row = Wq + (size_t)c * 256;
        float s = 0.0f;
        for (int cp = 0; cp < 256; ++cp) s = fmaf(row[cp], sw1[cp * 32 + j], s);
        wqt[c * 32 + j] = s;
    } else {                   // qtc = pb2@sw1 + sb1
        int j = e - 101376;
        if (j < 32) {
            float s = sb1[j];
            for (int c = 0; c < 256; ++c) s = fmaf(pb2[c], sw1[c * 32 + j], s);
            qtc[j] = s;
        }
    }
}

// ---------------- qprep2: LN1 ; qt = qtc - xln@Wqt  (4 rows/block) ----------------
__global__ __launch_bounds__(256)
void qprep2(const float* __restrict__ qin,
            const float* __restrict__ ln1g, const float* __restrict__ ln1b,
            const float* __restrict__ wqt, const float* __restrict__ qtc,
            float* __restrict__ qt)
{
    __shared__ __align__(16) float xlnL[4][CC];
    const int t = threadIdx.x;
    const int lane = t & 63;
    const int r = t >> 6;
    const int b0 = blockIdx.x * 4;
    const size_t rowoff = (size_t)(b0 + r) * CC;

    float v0 = qin[rowoff + lane];
    float v1 = qin[rowoff + lane + 64];
    float v2 = qin[rowoff + lane + 128];
    float v3 = qin[rowoff + lane + 192];
    float s = v0 + v1 + v2 + v3;
    #pragma unroll
    for (int off = 32; off > 0; off >>= 1) s += __shfl_xor(s, off);
    float mean = s * (1.0f / CC);
    float d0 = v0 - mean, d1 = v1 - mean, d2 = v2 - mean, d3 = v3 - mean;
    float vs = d0 * d0 + d1 * d1 + d2 * d2 + d3 * d3;
    #pragma unroll
    for (int off = 32; off > 0; off >>= 1) vs += __shfl_xor(vs, off);
    float rstd = rsqrtf(vs * (1.0f / CC) + EPSL);
    xlnL[r][lane]       = d0 * rstd * ln1g[lane] + ln1b[lane];
    xlnL[r][lane + 64]  = d1 * rstd * ln1g[lane + 64] + ln1b[lane + 64];
    xlnL[r][lane + 128] = d2 * rstd * ln1g[lane + 128] + ln1b[lane + 128];
    xlnL[r][lane + 192] = d3 * rstd * ln1g[lane + 192] + ln1b[lane + 192];
    __syncthreads();

    if (t < 128) {
        int r2 = t >> 5, j = t & 31;
        float acc = qtc[j];
        for (int c = 0; c < 256; ++c) acc = fmaf(-xlnL[r2][c], wqt[c * 32 + j], acc);
        qt[(size_t)(b0 + r2) * 32 + j] = acc;
    }
}

// ---------------- attn: per (b,h), 256 threads / 4 waves ----------------
// Phase 0 (row-split): stage K bf16 into swizzled keyb; pos-MLP hidden -> aux; vis ballot.
// Phase 1 (row-split): H = relu((K|ph)@Wt + qterm) -> aux (swizzled).
// Phase 2 (ct-split, 4 ct/wave): single pass with per-lane ONLINE softmax, unroll 2
//   (unroll 8 spilled in R4: WRITE_SIZE 228MB; unroll 2 matches R1's spill-free 92 VGPR).
__global__ __launch_bounds__(256, 2)
void cft_attn(const float* __restrict__ kin, const float* __restrict__ rel,
              const int* __restrict__ vis,
              const float* __restrict__ pw1, const float* __restrict__ pb1,
              const float* __restrict__ pb2, const float* __restrict__ sb2,
              const unsigned short* __restrict__ ws16,
              const float* __restrict__ qt,
              float* __restrict__ aggout)
{
    __shared__ __align__(16) unsigned char smem[81920];
    unsigned short* keyb = (unsigned short*)smem;            // [128][256] us, 16B-unit XOR swizzle (u ^= row&7)
    unsigned short* aux  = (unsigned short*)(smem + 65536);  // [128][64] us: H units 0-3, ph units 4-7, same swizzle

    const int bh = blockIdx.x;
    const int t = threadIdx.x;
    const int lane = t & 63;
    const int wvid = t >> 6;
    const int quad = lane >> 4;
    const int l16 = lane & 15;
    const int rb_w = wvid * 32;

    // ---- phase 0 ----
    const float4* kb4 = (const float4*)(kin + (size_t)bh * NN * CC);
    #pragma unroll
    for (int i = 0; i < 32; ++i) {
        int flat = i * 256 + t;
        int row = flat >> 6;
        int cu = flat & 63;                      // 8-byte unit within row
        float4 kv = kb4[flat];
        uint2 pk;
        pk.x = pack2(kv.x, kv.y);
        pk.y = pack2(kv.z, kv.w);
        int us = row * 256 + ((((cu >> 1) ^ (row & 7)) << 3) | ((cu & 1) << 2));
        *(uint2*)&keyb[us] = pk;
    }
    const unsigned long long vm0 = __ballot(vis[(size_t)bh * NN + lane] != 0);
    const unsigned long long vm1 = __ballot(vis[(size_t)bh * NN + 64 + lane] != 0);

    union { s16x8 v; unsigned short u[8]; } phf0, phf1;
    const int prow0 = rb_w + l16, prow1 = rb_w + 16 + l16;
    {
        float4 r40 = *(const float4*)(rel + ((size_t)bh * NN + prow0) * 4);
        float4 r41 = *(const float4*)(rel + ((size_t)bh * NN + prow1) * 4);
        #pragma unroll
        for (int j = 0; j < 8; ++j) {
            int col = quad * 8 + j;
            float w0 = pw1[col], w1 = pw1[32 + col], w2 = pw1[64 + col], w3 = pw1[96 + col];
            float b = pb1[col];
            float v0 = fmaf(r40.x, w0, fmaf(r40.y, w1, fmaf(r40.z, w2, fmaf(r40.w, w3, b))));
            float v1 = fmaf(r41.x, w0, fmaf(r41.y, w1, fmaf(r41.z, w2, fmaf(r41.w, w3, b))));
            phf0.u[j] = f2b(fmaxf(v0, 0.0f));
            phf1.u[j] = f2b(fmaxf(v1, 0.0f));
        }
        *(s16x8*)&aux[prow0 * 64 + (((4 + quad) ^ (prow0 & 7)) << 3)] = phf0.v;
        *(s16x8*)&aux[prow1 * 64 + (((4 + quad) ^ (prow1 & 7)) << 3)] = phf1.v;
    }
    const float qt0 = qt[(size_t)bh * 32 + l16];
    const float qt1 = qt[(size_t)bh * 32 + 16 + l16];
    __syncthreads();

    // ---- phase 1: H-GEMM (row-split) ----
    {
        const unsigned short* wst = ws16 + WTOFF;
        const int r0 = rb_w + l16;
        const int r1 = rb_w + 16 + l16;
        const int sw0 = r0 & 7;                  // == r1 & 7
        f32x4 hacc[2][2];
        #pragma unroll
        for (int mt = 0; mt < 2; ++mt)
            #pragma unroll
            for (int jt = 0; jt < 2; ++jt) hacc[mt][jt] = (f32x4){0.f, 0.f, 0.f, 0.f};
        #pragma unroll
        for (int kt = 0; kt < 8; ++kt) {
            s16x8 A0 = *(const s16x8*)&keyb[r0 * 256 + (((kt * 4 + quad) ^ sw0) << 3)];
            s16x8 A1 = *(const s16x8*)&keyb[r1 * 256 + (((kt * 4 + quad) ^ sw0) << 3)];
            #pragma unroll
            for (int jt = 0; jt < 2; ++jt) {
                s16x8 B = *(const s16x8*)(wst + (size_t)(jt * 9 + kt) * 512 + lane * 8);
                hacc[0][jt] = __builtin_amdgcn_mfma_f32_16x16x32_bf16(A0, B, hacc[0][jt], 0, 0, 0);
                hacc[1][jt] = __builtin_amdgcn_mfma_f32_16x16x32_bf16(A1, B, hacc[1][jt], 0, 0, 0);
            }
        }
        #pragma unroll
        for (int jt = 0; jt < 2; ++jt) {
            s16x8 B = *(const s16x8*)(wst + (size_t)(jt * 9 + 8) * 512 + lane * 8);
            hacc[0][jt] = __builtin_amdgcn_mfma_f32_16x16x32_bf16(phf0.v, B, hacc[0][jt], 0, 0, 0);
            hacc[1][jt] = __builtin_amdgcn_mfma_f32_16x16x32_bf16(phf1.v, B, hacc[1][jt], 0, 0, 0);
        }
        #pragma unroll
        for (int mt = 0; mt < 2; ++mt)
            #pragma unroll
            for (int jt = 0; jt < 2; ++jt) {
                float qv = jt ? qt1 : qt0;
                #pragma unroll
                for (int r = 0; r < 4; ++r) {
                    int n = rb_w + mt * 16 + quad * 4 + r;
                    int col = jt * 16 + l16;
                    aux[n * 64 + (((col >> 3) ^ (n & 7)) << 3) + (col & 7)] =
                        f2b(fmaxf(hacc[mt][jt][r] + qv, 0.0f));
                }
            }
    }
    __syncthreads();

    // ---- phase 2: ct-split, single pass, online softmax ----
    const unsigned short* wsv = ws16 + WVOFF;
    const unsigned short* ws2 = ws16 + SW2OFF;

    #pragma unroll 1
    for (int ck = 0; ck < 2; ++ck) {
        const int ct0 = wvid * 4 + ck * 2;
        s16x8 Bs0 = *(const s16x8*)(ws2 + ((size_t)ct0 * 64 + lane) * 8);
        s16x8 Bs1 = *(const s16x8*)(ws2 + ((size_t)(ct0 + 1) * 64 + lane) * 8);
        const float sb2c0 = sb2[ct0 * 16 + l16];
        const float sb2c1 = sb2[(ct0 + 1) * 16 + l16];
        const float pbv0 = pb2[ct0 * 16 + l16];
        const float pbv1 = pb2[(ct0 + 1) * 16 + l16];

        s16x8 Bv0[9], Bv1[9];
        #pragma unroll
        for (int kt = 0; kt < 9; ++kt) {
            Bv0[kt] = *(const s16x8*)(wsv + (size_t)(ct0 * 9 + kt) * 512 + lane * 8);
            Bv1[kt] = *(const s16x8*)(wsv + (size_t)((ct0 + 1) * 9 + kt) * 512 + lane * 8);
        }

        float ml0 = -3.0e38f, ml1 = -3.0e38f;
        float ls0 = 0.f, ls1 = 0.f, agg0 = 0.f, agg1 = 0.f;

        #pragma unroll 2
        for (int rb = 0; rb < 8; ++rb) {
            const int n0 = rb * 16 + l16;
            const int sw0 = n0 & 7;
            const unsigned short* arow = &keyb[n0 * 256];
            s16x8 H  = *(const s16x8*)&aux[n0 * 64 + ((quad ^ sw0) << 3)];
            s16x8 PH = *(const s16x8*)&aux[n0 * 64 + (((4 + quad) ^ sw0) << 3)];
            f32x4 a0 = (f32x4){0.f, 0.f, 0.f, 0.f};
            f32x4 a1 = (f32x4){0.f, 0.f, 0.f, 0.f};
            a0 = __builtin_amdgcn_mfma_f32_16x16x32_bf16(H, Bs0, a0, 0, 0, 0);
            a1 = __builtin_amdgcn_mfma_f32_16x16x32_bf16(H, Bs1, a1, 0, 0, 0);
            f32x4 v0a = (f32x4){0.f, 0.f, 0.f, 0.f};
            f32x4 v1a = (f32x4){0.f, 0.f, 0.f, 0.f};
            #pragma unroll
            for (int kt = 0; kt < 8; ++kt) {
                s16x8 A = *(const s16x8*)&arow[(((kt * 4 + quad) ^ sw0) << 3)];
                v0a = __builtin_amdgcn_mfma_f32_16x16x32_bf16(A, Bv0[kt], v0a, 0, 0, 0);
                v1a = __builtin_amdgcn_mfma_f32_16x16x32_bf16(A, Bv1[kt], v1a, 0, 0, 0);
            }
            v0a = __builtin_amdgcn_mfma_f32_16x16x32_bf16(PH, Bv0[8], v0a, 0, 0, 0);
            v1a = __builtin_amdgcn_mfma_f32_16x16x32_bf16(PH, Bv1[8], v1a, 0, 0, 0);

            const unsigned long long m = (rb < 4) ? vm0 : vm1;
            const int nb = (rb * 16) & 63;
            float sc0[4], sc1[4];
            #pragma unroll
            for (int r = 0; r < 4; ++r) {
                bool vv = (m >> (nb + quad * 4 + r)) & 1;
                sc0[r] = vv ? (a0[r] + sb2c0) : -1e9f;
                sc1[r] = vv ? (a1[r] + sb2c1) : -1e9f;
            }
            // online update ct0
            {
                float pm = fmaxf(fmaxf(sc0[0], sc0[1]), fmaxf(sc0[2], sc0[3]));
                float mn = fmaxf(ml0, pm);
                float scl = __expf(ml0 - mn);
                float e0 = __expf(sc0[0] - mn);
                float e1 = __expf(sc0[1] - mn);
                float e2 = __expf(sc0[2] - mn);
                float e3 = __expf(sc0[3] - mn);
                float sls = e0 + e1 + e2 + e3;
                float sag = fmaf(e0, v0a[0] + pbv0,
                            fmaf(e1, v0a[1] + pbv0,
                            fmaf(e2, v0a[2] + pbv0,
                                 e3 * (v0a[3] + pbv0))));
                ls0 = fmaf(ls0, scl, sls);
                agg0 = fmaf(agg0, scl, sag);
                ml0 = mn;
            }
            // online update ct1
            {
                float pm = fmaxf(fmaxf(sc1[0], sc1[1]), fmaxf(sc1[2], sc1[3]));
                float mn = fmaxf(ml1, pm);
                float scl = __expf(ml1 - mn);
                float e0 = __expf(sc1[0] - mn);
                float e1 = __expf(sc1[1] - mn);
                float e2 = __expf(sc1[2] - mn);
                float e3 = __expf(sc1[3] - mn);
                float sls = e0 + e1 + e2 + e3;
                float sag = fmaf(e0, v1a[0] + pbv1,
                            fmaf(e1, v1a[1] + pbv1,
                            fmaf(e2, v1a[2] + pbv1,
                                 e3 * (v1a[3] + pbv1))));
                ls1 = fmaf(ls1, scl, sls);
                agg1 = fmaf(agg1, scl, sag);
                ml1 = mn;
            }
        }

        // quad-merge: rescale by exp(m - mg), then sum
        float mg0 = fmaxf(ml0, __shfl_xor(ml0, 16));
        mg0 = fmaxf(mg0, __shfl_xor(mg0, 32));
        float f0 = __expf(ml0 - mg0);
        agg0 *= f0; ls0 *= f0;
        float mg1 = fmaxf(ml1, __shfl_xor(ml1, 16));
        mg1 = fmaxf(mg1, __shfl_xor(mg1, 32));
        float f1 = __expf(ml1 - mg1);
        agg1 *= f1; ls1 *= f1;

        agg0 += __shfl_xor(agg0, 16); agg0 += __shfl_xor(agg0, 32);
        ls0  += __shfl_xor(ls0, 16);  ls0  += __shfl_xor(ls0, 32);
        agg1 += __shfl_xor(agg1, 16); agg1 += __shfl_xor(agg1, 32);
        ls1  += __shfl_xor(ls1, 16);  ls1  += __shfl_xor(ls1, 32);
        if (lane < 16) {
            aggout[(size_t)bh * CC + ct0 * 16 + l16]       = agg0 / ls0;
            aggout[(size_t)bh * CC + (ct0 + 1) * 16 + l16] = agg1 / ls1;
        }
    }
}

// ---------------- ffo2: Wo + LN2 + FF, 2 rows/block, packed uint weight loads ----------------
__global__ __launch_bounds__(256, 4)
void cft_ffo2(const float* __restrict__ aggp, const float* __restrict__ qin,
              const float* __restrict__ bo,
              const float* __restrict__ ln2g, const float* __restrict__ ln2b,
              const unsigned short* __restrict__ ws16,
              const float* __restrict__ fb1, const float* __restrict__ fb2,
              float* __restrict__ out)
{
    __shared__ __align__(16) float aggL[2][CC];
    __shared__ __align__(16) float xlnL[2][CC];
    __shared__ __align__(16) float ffh[2][HIDN];
    __shared__ __align__(16) float part[2][2][CC];   // [half][row][c]
    __shared__ float red[4];
    const int t = threadIdx.x;
    const int b0 = blockIdx.x * 2;
    const unsigned short* wob  = ws16 + WOB_OFF;
    const unsigned short* fw1b = ws16 + FW1B_OFF;
    const unsigned short* fw2b = ws16 + FW2B_OFF;

    float xq[2];
    #pragma unroll
    for (int i = 0; i < 2; ++i) {
        aggL[i][t] = aggp[(size_t)(b0 + i) * CC + t];
        xq[i] = qin[(size_t)(b0 + i) * CC + t];
    }
    __syncthreads();

    // Wo matvec (c = t)
    float ao[2];
    { float b = bo[t]; ao[0] = b; ao[1] = b; }
    for (int k4 = 0; k4 < CC / 4; ++k4) {
        float4 a0 = *(const float4*)&aggL[0][k4 * 4];
        float4 a1 = *(const float4*)&aggL[1][k4 * 4];
        const unsigned short* w = wob + (size_t)(k4 * 4) * CC + t;
        float w0 = b2f(w[0]), w1 = b2f(w[CC]), w2 = b2f(w[2 * CC]), w3 = b2f(w[3 * CC]);
        ao[0] = fmaf(a0.x, w0, fmaf(a0.y, w1, fmaf(a0.z, w2, fmaf(a0.w, w3, ao[0]))));
        ao[1] = fmaf(a1.x, w0, fmaf(a1.y, w1, fmaf(a1.z, w2, fmaf(a1.w, w3, ao[1]))));
    }
    float xrs[2] = { ao[0] + xq[0], ao[1] + xq[1] };

    // LN2
    #pragma unroll
    for (int row = 0; row < 2; ++row) {
        float x = xrs[row];
        float mean = block_sum_256(x, red) * (1.0f / CC);
        float d = x - mean;
        float var = block_sum_256(d * d, red) * (1.0f / CC);
        xlnL[row][t] = d * rsqrtf(var + EPSL) * ln2g[t] + ln2b[t];
    }
    __syncthreads();

    // ff1: h = {2t, 2t+1, 2t+512, 2t+513}; packed uint loads (4B/lane)
    {
        const int h0 = 2 * t;
        float acc[2][4];
        acc[0][0] = acc[1][0] = fb1[h0];
        acc[0][1] = acc[1][1] = fb1[h0 + 1];
        acc[0][2] = acc[1][2] = fb1[h0 + 512];
        acc[0][3] = acc[1][3] = fb1[h0 + 513];
        for (int k4 = 0; k4 < CC / 4; ++k4) {
            float4 x0 = *(const float4*)&xlnL[0][k4 * 4];
            float4 x1 = *(const float4*)&xlnL[1][k4 * 4];
            float xa0[4] = {x0.x, x0.y, x0.z, x0.w};
            float xa1[4] = {x1.x, x1.y, x1.z, x1.w};
            #pragma unroll
            for (int kk = 0; kk < 4; ++kk) {
                const int k = k4 * 4 + kk;
                unsigned wA = *(const unsigned*)&fw1b[(size_t)k * HIDN + h0];
                unsigned wB = *(const unsigned*)&fw1b[(size_t)k * HIDN + h0 + 512];
                float wl = blo(wA), wh = bhi(wA), wl2 = blo(wB), wh2 = bhi(wB);
                acc[0][0] = fmaf(xa0[kk], wl, acc[0][0]);
                acc[0][1] = fmaf(xa0[kk], wh, acc[0][1]);
                acc[0][2] = fmaf(xa0[kk], wl2, acc[0][2]);
                acc[0][3] = fmaf(xa0[kk], wh2, acc[0][3]);
                acc[1][0] = fmaf(xa1[kk], wl, acc[1][0]);
                acc[1][1] = fmaf(xa1[kk], wh, acc[1][1]);
                acc[1][2] = fmaf(xa1[kk], wl2, acc[1][2]);
                acc[1][3] = fmaf(xa1[kk], wh2, acc[1][3]);
            }
        }
        #pragma unroll
        for (int row = 0; row < 2; ++row) {
            ffh[row][h0]       = fmaxf(acc[row][0], 0.0f);
            ffh[row][h0 + 1]   = fmaxf(acc[row][1], 0.0f);
            ffh[row][h0 + 512] = fmaxf(acc[row][2], 0.0f);
            ffh[row][h0 + 513] = fmaxf(acc[row][3], 0.0f);
        }
    }
    __syncthreads();

    // ff2: half the threads per h-half, c-pairs; packed uint loads
    {
        const int u = t & 127;
        const int half = t >> 7;
        const int c0 = 2 * u;
        const int hbase = half * 512;
        float oacc[2][2] = {{0.f, 0.f}, {0.f, 0.f}};   // [row][c-slot]
        for (int h4 = 0; h4 < 128; ++h4) {
            const int h = hbase + h4 * 4;
            #pragma unroll
            for (int hh = 0; hh < 4; ++hh) {
                unsigned w = *(const unsigned*)&fw2b[(size_t)(h + hh) * CC + c0];
                float w0 = blo(w), w1 = bhi(w);
                float hv0 = ffh[0][h + hh];
                float hv1 = ffh[1][h + hh];
                oacc[0][0] = fmaf(hv0, w0, oacc[0][0]);
                oacc[0][1] = fmaf(hv0, w1, oacc[0][1]);
                oacc[1][0] = fmaf(hv1, w0, oacc[1][0]);
                oacc[1][1] = fmaf(hv1, w1, oacc[1][1]);
            }
        }
        part[half][0][c0]     = oacc[0][0];
        part[half][0][c0 + 1] = oacc[0][1];
        part[half][1][c0]     = oacc[1][0];
        part[half][1][c0 + 1] = oacc[1][1];
    }
    __syncthreads();
    #pragma unroll
    for (int row = 0; row < 2; ++row)
        out[(size_t)(b0 + row) * CC + t] =
            xrs[row] + fb2[t] + part[0][row][t] + part[1][row][t];
}

extern "C" void kernel_launch(void* const* d_in, const int* in_sizes, int n_in,
                              void* d_out, int out_size, void* d_ws, size_t ws_size,
                              hipStream_t stream) {
    const float* qin  = (const float*)d_in[0];
    const float* kin  = (const float*)d_in[1];
    const float* rel  = (const float*)d_in[2];
    const int*   vis  = (const int*)  d_in[3];
    const float* ln1g = (const float*)d_in[4];
    const float* ln1b = (const float*)d_in[5];
    const float* ln2g = (const float*)d_in[6];
    const float* ln2b = (const float*)d_in[7];
    const float* Wq   = (const float*)d_in[8];
    const float* Wk   = (const float*)d_in[9];
    const float* Wv   = (const float*)d_in[10];
    const float* pw1  = (const float*)d_in[11];
    const float* pb1  = (const float*)d_in[12];
    const float* pw2  = (const float*)d_in[13];
    const float* pb2  = (const float*)d_in[14];
    const float* sw1  = (const float*)d_in[15];
    const float* sb1  = (const float*)d_in[16];
    const float* sw2  = (const float*)d_in[17];
    const float* sb2  = (const float*)d_in[18];
    const float* Wo   = (const float*)d_in[19];
    const float* bo   = (const float*)d_in[20];
    const float* fw1  = (const float*)d_in[21];
    const float* fb1  = (const float*)d_in[22];
    const float* fw2  = (const float*)d_in[23];
    const float* fb2  = (const float*)d_in[24];
    (void)in_sizes; (void)n_in; (void)out_size; (void)ws_size;

    unsigned short* ws16 = (unsigned short*)d_ws;
    float* qt   = (float*)((char*)d_ws + QT_BYTE_OFF);
    float* aggb = (float*)((char*)d_ws + AGG_BYTE_OFF);
    float* wqt  = (float*)((char*)d_ws + WQT_BYTE_OFF);
    float* qtc  = (float*)((char*)d_ws + QTC_BYTE_OFF);
    float* o = (float*)d_out;

    prep_all<<<dim3(397), dim3(256), 0, stream>>>(
        Wk, Wv, Wq, pw2, sw1, sw2, fw1, fw2, Wo, pb2, sb1, ws16, wqt, qtc);
    qprep2<<<dim3(256), dim3(256), 0, stream>>>(qin, ln1g, ln1b, wqt, qtc, qt);
    cft_attn<<<dim3(1024), dim3(256), 0, stream>>>(
        kin, rel, vis, pw1, pb1, pb2, sb2, ws16, qt, aggb);
    cft_ffo2<<<dim3(512), dim3(256), 0, stream>>>(
        aggb, qin, bo, ln2g, ln2b, ws16, fb1, fb2, o);
}